// Round 19
// baseline (276.046 us; speedup 1.0000x reference)
//
#include <hip/hip_runtime.h>
#include <math.h>
#include <float.h>

#define BB 32
#define CC 64
#define KK 8192
#define NPIX 256
#define NELEM (BB*CC*NPIX)  // 524288

typedef unsigned short u16;
typedef __attribute__((ext_vector_type(8))) short bf16x8;
typedef __attribute__((ext_vector_type(4))) float f32x4;

__device__ __forceinline__ u16 f2bf(float v) {   // RNE f32->bf16
  unsigned u = __float_as_uint(v);
  return (u16)((u + 0x7FFFu + ((u >> 16) & 1u)) >> 16);
}

// init zr/out + wsq (+ -wsq/2) + ehi(bf16 pack of emb) in one launch
__global__ void k_prep(const float* __restrict__ f, float* __restrict__ zr,
                       float* __restrict__ out, const float* __restrict__ emb,
                       float* __restrict__ wsq32, float* __restrict__ nhw,
                       u16* __restrict__ ehi) {
  int i = blockIdx.x * 256 + threadIdx.x;
  if (i < NELEM) { zr[i] = f[i]; out[i] = 0.f; ehi[i] = f2bf(emb[i]); }
  if (i < KK) {
    const float* row = emb + i * 64;
    double s = 0.0;
    #pragma unroll
    for (int c = 0; c < 64; ++c) s += (double)row[c] * (double)row[c];
    float w = (float)s;
    wsq32[i] = w;            // same-binade f32: argmin-safe (scheme-free)
    nhw[i] = -0.5f * w;      // prefilter accumulator init
  }
}

// numpy-exact area mean for si0 (pn=1): feeds exact argmin path
__global__ void k_down(const float* __restrict__ zr, float* __restrict__ zd, int pn) {
#pragma clang fp contract(off)
  int i = blockIdx.x * 256 + threadIdx.x;
  int pnpn = pn * pn;
  int n = BB * CC * pnpn;
  if (i >= n) return;
  int x = i % pn; int y = (i / pn) % pn; int bc = i / pnpn;
  int bs = 16 / pn;
  const float* src = zr + bc * NPIX + (y * bs) * 16 + x * bs;
  float acc = 0.f;
  for (int dy = 0; dy < bs; ++dy) {
    const float* a = src + dy * 16;
    float s;
    if (bs == 16) {
      float r[8];
      #pragma unroll
      for (int j = 0; j < 8; ++j) r[j] = a[j] + a[8 + j];
      s = ((r[0] + r[1]) + (r[2] + r[3])) + ((r[4] + r[5]) + (r[6] + r[7]));
    } else if (bs == 8) {
      s = ((a[0] + a[1]) + (a[2] + a[3])) + ((a[4] + a[5]) + (a[6] + a[7]));
    } else if (bs == 4) {
      s = ((a[0] + a[1]) + a[2]) + a[3];
    } else {
      s = a[0] + a[1];
    }
    acc = acc + s;
  }
  zd[i] = acc * (1.f / (bs * bs));
}

// pack for MFMA path: lane-per-channel. bs=1 (si4), 2 (si3), 4 (si2), 8 (si1):
// fused numpy-exact area mean. Writes zhi(bf16), zt32(f32), zsq32.
__global__ __launch_bounds__(256) void k_pack(
    const float* __restrict__ zr, int pn, int bs,
    u16* __restrict__ zhi, float* __restrict__ zt32, float* __restrict__ zsq32) {
#pragma clang fp contract(off)
  int tid = threadIdx.x;
  int lv = tid >> 6, c = tid & 63;
  int vec = blockIdx.x * 4 + lv;
  int pnpn = pn * pn;
  int b = vec / pnpn, p = vec % pnpn;
  int y = p / pn, x = p % pn;
  const float* src = zr + ((size_t)(b * 64 + c)) * 256 + (y * bs) * 16 + x * bs;
  float v;
  if (bs == 1) {
    v = src[0];
  } else if (bs == 2) {   // rows: a0+a1; sequential rows; * exact 0.25
    v = (src[0] + src[1]) + (src[16] + src[17]);
    v = v * 0.25f;
  } else if (bs == 4) {   // rows ((a0+a1)+a2)+a3; seq rows; * 1/16
    float acc = 0.f;
    #pragma unroll
    for (int dy = 0; dy < 4; ++dy) {
      const float* a = src + dy * 16;
      float s = ((a[0] + a[1]) + a[2]) + a[3];
      acc = acc + s;
    }
    v = acc * 0.0625f;
  } else {                // bs==8: pairwise-tree rows; seq rows; * 1/64
    float acc = 0.f;
    #pragma unroll
    for (int dy = 0; dy < 8; ++dy) {
      const float* a = src + dy * 16;
      float s = ((a[0] + a[1]) + (a[2] + a[3])) + ((a[4] + a[5]) + (a[6] + a[7]));
      acc = acc + s;
    }
    v = acc * 0.015625f;
  }
  zhi[(size_t)vec * 64 + c] = f2bf(v);
  zt32[(size_t)vec * 64 + c] = v;
  double sq = (double)v * (double)v;
  #pragma unroll
  for (int m = 1; m < 64; m <<= 1)
    sq += __shfl_xor(sq, m, 64);        // f64 all-reduce: order-independent to 1e-15
  if (c == 0) zsq32[vec] = (float)sq;
}

// ---- argmin, si0 only (exact path, proven) ----
__global__ __launch_bounds__(256, 4) void k_argmin(
    const float* __restrict__ zd, const float* __restrict__ emb,
    const float* __restrict__ wsq32,
    float* __restrict__ pd, int* __restrict__ pi,
    int numVec, int pnpn, int kchunk) {
#pragma clang fp contract(off)
  __shared__ __align__(16) float zt[32][68];
  __shared__ __align__(16) float et[64 * 64];
  __shared__ float ws_s[64];
  __shared__ float red_d[256];
  __shared__ int   red_i[256];
  int tid = threadIdx.x;
  int v0 = blockIdx.x * 32;
  int kbase = blockIdx.y * kchunk;

  for (int idx = tid; idx < 32 * 64; idx += 256) {
    int v = idx >> 6, c = idx & 63;
    int vi = v0 + v;
    float val = 0.f;
    if (vi < numVec) {
      int b = vi / pnpn, p = vi % pnpn;
      val = zd[(b * 64 + c) * pnpn + p];
    }
    zt[v][c] = val;
  }
  __syncthreads();

  const int v = tid & 31, kg = tid >> 5;
  float4 z4[16];
  #pragma unroll
  for (int i = 0; i < 16; ++i) z4[i] = *reinterpret_cast<float4*>(&zt[v][i * 4]);
  float zsq = 0.f;
  #pragma unroll
  for (int i = 0; i < 16; ++i)
    zsq += z4[i].x * z4[i].x + z4[i].y * z4[i].y + z4[i].z * z4[i].z + z4[i].w * z4[i].w;

  float bd = FLT_MAX; int bi = 0x7fffffff;
  for (int k0 = 0; k0 < kchunk; k0 += 64) {
    __syncthreads();
    {
      const float4* gsrc = reinterpret_cast<const float4*>(emb + (size_t)(kbase + k0) * 64);
      float4* ldst = reinterpret_cast<float4*>(et);
      #pragma unroll
      for (int idx = 0; idx < 4; ++idx)
        ldst[tid + idx * 256] = gsrc[tid + idx * 256];
    }
    if (tid < 64) ws_s[tid] = wsq32[kbase + k0 + tid];
    __syncthreads();
    #pragma unroll
    for (int j = 0; j < 8; ++j) {
      int kl = kg * 8 + j;
      const float4* e4 = reinterpret_cast<const float4*>(&et[kl * 64]);
      float acc = 0.f;
      #pragma unroll
      for (int i = 0; i < 16; ++i) {
        float4 e = e4[i];
        acc = __builtin_fmaf(z4[i].x, e.x, acc);
        acc = __builtin_fmaf(z4[i].y, e.y, acc);
        acc = __builtin_fmaf(z4[i].z, e.z, acc);
        acc = __builtin_fmaf(z4[i].w, e.w, acc);
      }
      float t1 = zsq + ws_s[kl];
      float d  = t1 - 2.0f * acc;
      if (d < bd) { bd = d; bi = kbase + k0 + kl; }
    }
  }
  red_d[tid] = bd; red_i[tid] = bi;
  __syncthreads();
  if (tid < 32) {
    float fb = red_d[tid]; int fi = red_i[tid];
    #pragma unroll
    for (int g = 1; g < 8; ++g) {
      float cd = red_d[g * 32 + tid]; int ci = red_i[g * 32 + tid];
      if (cd < fb || (cd == fb && ci < fi)) { fb = cd; fi = ci; }
    }
    int vi = v0 + tid;
    if (vi < numVec) {
      pd[blockIdx.y * numVec + vi] = fb;
      pi[blockIdx.y * numVec + vi] = fi;
    }
  }
}

// ---- argmin big scales: bf16 MFMA prefilter, MAX-form packed keys,
// ASYNC double-buffer at (256,4): prefetch next tile to registers during
// compute; ds_write after compute (proven r17: no spill, FETCH sane).
__global__ __launch_bounds__(256, 4) void k_argmin_mfma(
    const u16* __restrict__ zhi, const u16* __restrict__ ehi,
    const float* __restrict__ nhw, float* __restrict__ cdp,
    int numVec, int part) {
  __shared__ u16  es[2][64 * 72];
  __shared__ float wss[2][64];
  const int tid = threadIdx.x;
  const int wid = tid >> 6, lane = tid & 63;
  const int l15 = lane & 15, l4 = lane >> 4;
  const int vw = blockIdx.x * 128 + wid * 32;
  const int kbase = blockIdx.y * part;
  const int KSx = gridDim.y;

  bf16x8 za[2][2];
  #pragma unroll
  for (int s = 0; s < 2; ++s) {
    const u16* zp = zhi + (size_t)(vw + s * 16 + l15) * 64 + l4 * 8;
    za[s][0] = *reinterpret_cast<const bf16x8*>(zp);
    za[s][1] = *reinterpret_cast<const bf16x8*>(zp + 32);
  }

  float d1[2][4], d2[2][4];
  #pragma unroll
  for (int s = 0; s < 2; ++s)
    #pragma unroll
    for (int r = 0; r < 4; ++r) { d1[s][r] = -FLT_MAX; d2[s][r] = -FLT_MAX; }

  const int NT = part >> 6;
  bf16x8 r0, r1; float wreg = 0.f;
  const int scode = tid >> 2, sseg = tid & 3;

  #define LOADT(t)                                                           \
    { const bf16x8* s8 = reinterpret_cast<const bf16x8*>(                    \
          ehi + (size_t)(kbase + (t) * 64) * 64 + scode * 64 + sseg * 16);   \
      r0 = s8[0]; r1 = s8[1];                                                \
      if (tid < 64) wreg = nhw[kbase + (t) * 64 + tid]; }
  #define WRITET(buf)                                                        \
    { bf16x8* d8 = reinterpret_cast<bf16x8*>(&es[buf][scode * 72 + sseg * 16]); \
      d8[0] = r0; d8[1] = r1;                                                \
      if (tid < 64) wss[buf][tid] = wreg; }

  LOADT(0); WRITET(0);
  __syncthreads();
  for (int t = 0; t < NT; ++t) {
    int cur = t & 1;
    if (t + 1 < NT) LOADT(t + 1);        // in-flight during compute
    #pragma unroll
    for (int ct = 0; ct < 4; ++ct) {
      const u16* eb = &es[cur][(ct * 16 + l15) * 72 + l4 * 8];
      bf16x8 b0 = *reinterpret_cast<const bf16x8*>(eb);
      bf16x8 b1 = *reinterpret_cast<const bf16x8*>(eb + 32);
      float hwl = wss[cur][ct * 16 + l15];           // = -wsq/2
      unsigned idu = (unsigned)(t * 64 + ct * 16 + l15);   // < 256
      #pragma unroll
      for (int s = 0; s < 2; ++s) {
        f32x4 acc = {hwl, hwl, hwl, hwl};
        acc = __builtin_amdgcn_mfma_f32_16x16x32_bf16(za[s][0], b0, acc, 0, 0, 0);
        acc = __builtin_amdgcn_mfma_f32_16x16x32_bf16(za[s][1], b1, acc, 0, 0, 0);
        #pragma unroll
        for (int r = 0; r < 4; ++r) {
          // v_bfi_b32 pattern: (x & M) | (id & ~M)
          unsigned ku = (__float_as_uint(acc[r]) & 0xFFFFFF00u) | (idu & 0x000000FFu);
          float key = __uint_as_float(ku);
          float o1 = d1[s][r];
          d1[s][r] = fmaxf(o1, key);
          d2[s][r] = __builtin_amdgcn_fmed3f(o1, key, d2[s][r]);
        }
      }
    }
    if (t + 1 < NT) WRITET(cur ^ 1);     // vmcnt wait lands after compute
    __syncthreads();
  }

  // merge: top-2 per 8-lane half (masks 1,2,4), write 4 keys/part
  #pragma unroll
  for (int s = 0; s < 2; ++s)
    #pragma unroll
    for (int r = 0; r < 4; ++r) {
      float q0 = d1[s][r], q1 = d2[s][r];
      #pragma unroll
      for (int m = 1; m < 8; m <<= 1) {
        float p0 = __shfl_xor(q0, m), p1 = __shfl_xor(q1, m);
        { bool c0 = p0 > q0, c1 = p0 > q1;
          q1 = c0 ? q0 : (c1 ? p0 : q1);
          q0 = c0 ? p0 : q0; }
        { bool c0 = p1 > q0, c1 = p1 > q1;
          q1 = c0 ? q0 : (c1 ? p1 : q1);
          q0 = c0 ? p1 : q0; }
      }
      if ((l15 & 7) == 0) {
        int vec = vw + s * 16 + l4 * 4 + r;
        int half = l15 >> 3;
        size_t base = ((size_t)vec * KSx + blockIdx.y) * 4 + half * 2;
        cdp[base + 0] = q0; cdp[base + 1] = q1;
      }
    }
}

// exact rescore: wave-per-vector, lane-per-candidate (2 slots, ncand=128).
// keys are MAX-form (acc = dot - wl/2); band: key >= amax - band/2.
__global__ __launch_bounds__(256) void k_rescore(
    const float* __restrict__ cdp, const float* __restrict__ zt32,
    const float* __restrict__ emb, const float* __restrict__ wsq32,
    const float* __restrict__ zsq32,
    int* __restrict__ pi, int numVec, int ncand) {
#pragma clang fp contract(off)
  __shared__ float zsh[4][64];
  int tid = threadIdx.x;
  int wid = tid >> 6, lane = tid & 63;
  int v0 = blockIdx.x * 4;
  zsh[wid][lane] = zt32[(size_t)v0 * 64 + tid];
  __syncthreads();

  int vec = v0 + wid;
  float zsq = zsq32[vec];
  const float* cdb = cdp + (size_t)vec * ncand;
  float dv0 = cdb[lane];
  float dv1 = (ncand > 64) ? cdb[lane + 64] : -FLT_MAX;
  int j0 = lane, j1 = lane + 64;
  int ki0 = ((j0 >> 2) << 8) | (int)(__float_as_uint(dv0) & 0xFFu);
  int ki1 = ((j1 >> 2) << 8) | (int)(__float_as_uint(dv1) & 0xFFu);

  float amax = fmaxf(dv0, dv1);
  #pragma unroll
  for (int m = 1; m < 64; m <<= 1) amax = fmaxf(amax, __shfl_xor(amax, m, 64));
  float thr = amax - 0.5f * fmaf(sqrtf(zsq), 1.25e-5f, 1e-4f);

  const float* zw = zsh[wid];
  float d = FLT_MAX; int bi = 0x7fffffff;
  #pragma unroll
  for (int slot = 0; slot < 2; ++slot) {
    float dv = slot ? dv1 : dv0;
    int   kk = slot ? ki1 : ki0;
    if (dv >= thr) {
      const float4* er = reinterpret_cast<const float4*>(emb + (size_t)kk * 64);
      float4 e4[16];
      #pragma unroll
      for (int i = 0; i < 16; ++i) e4[i] = er[i];
      float acc = 0.f;
      #pragma unroll
      for (int i = 0; i < 16; ++i) {               // exact ascending-c chain
        acc = __builtin_fmaf(zw[4 * i + 0], e4[i].x, acc);
        acc = __builtin_fmaf(zw[4 * i + 1], e4[i].y, acc);
        acc = __builtin_fmaf(zw[4 * i + 2], e4[i].z, acc);
        acc = __builtin_fmaf(zw[4 * i + 3], e4[i].w, acc);
      }
      float t1 = zsq + wsq32[kk];
      float dd = t1 - 2.0f * acc;
      if (dd < d || (dd == d && kk < bi)) { d = dd; bi = kk; }
    }
  }
  #pragma unroll
  for (int m = 1; m < 64; m <<= 1) {
    float od = __shfl_xor(d, m, 64);
    int   oi = __shfl_xor(bi, m, 64);
    if (od < d || (od == d && oi < bi)) { d = od; bi = oi; }
  }
  if (lane == 0) pi[vec] = bi;
}

// ---- fused ksplit-reduce + cubic upsample (si0..si3; si4 fused into conv) ----
__global__ __launch_bounds__(256) void k_up(
    const float* __restrict__ pd, const int* __restrict__ pi,
    const float* __restrict__ emb, float* __restrict__ hup,
    int pn, int ksplit) {
  __shared__ float td[256];
  __shared__ int   ti[256];
  __shared__ int   tok_s[256];
  __shared__ float wsh[16][4];
  __shared__ int   i0sh[16];

  int t = threadIdx.x;
  int i = blockIdx.x * 256 + t;
  int p = i & 255; int c = (i >> 8) & 63; int b = i >> 14;
  int P = pn * pn;
  int numVec = BB * P;

  if (ksplit > 1) {
    int R = 256 / P;
    int v = t % P, sg = t / P;
    float bd = FLT_MAX; int bi = 0x7fffffff;
    for (int s = sg; s < ksplit; s += R) {
      float cd = pd[s * numVec + b * P + v]; int ci = pi[s * numVec + b * P + v];
      if (cd < bd || (cd == bd && ci < bi)) { bd = cd; bi = ci; }
    }
    td[t] = bd; ti[t] = bi;
    __syncthreads();
    for (int r = R >> 1; r >= 1; r >>= 1) {
      if (sg < r) {
        float cd = td[t + r * P]; int ci = ti[t + r * P];
        if (cd < td[t] || (cd == td[t] && ci < ti[t])) { td[t] = cd; ti[t] = ci; }
      }
      __syncthreads();
    }
    if (t < P) tok_s[t] = ti[t];
  } else {
    if (t < P) tok_s[t] = pi[b * P + t];   // rescore already reduced
  }
  if (pn < 16 && t < 16) {
    double s = (t + 0.5) * ((double)pn / 16.0) - 0.5;
    int i0 = (int)floor(s) - 1;
    int hi = pn - 4; if (hi < 0) hi = 0;
    if (i0 < 0) i0 = 0; if (i0 > hi) i0 = hi;
    double wv[4]; double sum = 0.0;
    #pragma unroll
    for (int qq = 0; qq < 4; ++qq) {
      int ii = i0 + qq;
      double w = 0.0;
      if (ii < pn) {
        double xx = fabs(s - (double)ii);
        if (xx < 1.0)       w = ((1.5 * xx - 2.5) * xx) * xx + 1.0;
        else if (xx < 2.0)  w = ((-0.5 * xx + 2.5) * xx - 4.0) * xx + 2.0;
      }
      wv[qq] = w; sum += w;
    }
    i0sh[t] = i0;
    #pragma unroll
    for (int qq = 0; qq < 4; ++qq) wsh[t][qq] = (float)(wv[qq] / sum);
  }
  __syncthreads();

  if (pn == 16) { hup[i] = emb[(size_t)tok_s[p] * 64 + c]; return; }

  int y = p >> 4, x = p & 15;
  int iy0 = i0sh[y], ix0 = i0sh[x];
  float acc = 0.f;
  #pragma unroll
  for (int ty = 0; ty < 4; ++ty) {
    float wy = wsh[y][ty];
    int iy = iy0 + ty; if (iy > pn - 1) iy = pn - 1;
    float tmp = 0.f;
    #pragma unroll
    for (int tx = 0; tx < 4; ++tx) {
      float wx = wsh[x][tx];
      int ix = ix0 + tx; if (ix > pn - 1) ix = pn - 1;
      tmp += wx * emb[(size_t)tok_s[iy * pn + ix] * 64 + c];
    }
    acc += wy * tmp;
  }
  hup[i] = acc;
}

// ---- conv (round-8 proven) + optional fused si4 gather (use_tok):
// h values read directly from emb[tok*64+c] — identical f32 values as hup.
__global__ __launch_bounds__(256) void k_conv(
    const float* __restrict__ hup, const float* __restrict__ w,
    const float* __restrict__ bias, float* __restrict__ out, float* __restrict__ zr,
    const int* __restrict__ tok, const float* __restrict__ emb, int use_tok) {
  __shared__ __align__(16) float ins[16][18 * 18];
  __shared__ __align__(16) float wsh[8 * 64 * 12];
  __shared__ int tok_s[256];
  int tid = threadIdx.x;
  int b = blockIdx.x;
  int ocb = blockIdx.y;

  for (int idx = tid; idx < 16 * 324; idx += 256)
    (&ins[0][0])[idx] = 0.f;
  for (int idx = tid; idx < 8 * 64 * 9; idx += 256) {
    int ocic = idx / 9, t = idx - ocic * 9;
    wsh[ocic * 12 + t] = w[(size_t)ocb * 8 * 64 * 9 + idx];
  }
  if (use_tok) tok_s[tid] = tok[b * 256 + tid];
  __syncthreads();   // tok_s visible before chunk-0 gather

  const int wid = tid >> 6, lane = tid & 63;
  const int ocg = wid >> 1;
  const int ph = (wid & 1) * 64 + lane;
  const int x = ph & 15, y2 = ph >> 4;

  float acc[4][2];
  #pragma unroll
  for (int j = 0; j < 4; ++j) {
    float bv = bias[ocb * 8 + ocg * 4 + j];
    acc[j][0] = bv; acc[j][1] = bv;
  }

  const float* hb = hup + (size_t)b * 64 * NPIX;
  float sreg[16];
  // chunk 0: (r maps to icl=r, p maps to tid)
  if (use_tok) {
    const float4* er = reinterpret_cast<const float4*>(emb + (size_t)tok_s[tid] * 64);
    #pragma unroll
    for (int q = 0; q < 4; ++q) {
      float4 v = er[q];
      sreg[q * 4 + 0] = v.x; sreg[q * 4 + 1] = v.y;
      sreg[q * 4 + 2] = v.z; sreg[q * 4 + 3] = v.w;
    }
  } else {
    #pragma unroll
    for (int r = 0; r < 16; ++r) sreg[r] = hb[r * 256 + tid];
  }

  for (int cc = 0; cc < 4; ++cc) {
    __syncthreads();
    #pragma unroll
    for (int r = 0; r < 16; ++r) {
      int idx = r * 256 + tid;
      int icl = idx >> 8, p = idx & 255;
      ins[icl][((p >> 4) + 1) * 18 + (p & 15) + 1] = sreg[r];
    }
    __syncthreads();
    if (cc < 3) {
      if (use_tok) {
        const float4* er = reinterpret_cast<const float4*>(
            emb + (size_t)tok_s[tid] * 64 + (cc + 1) * 16);
        #pragma unroll
        for (int q = 0; q < 4; ++q) {
          float4 v = er[q];
          sreg[q * 4 + 0] = v.x; sreg[q * 4 + 1] = v.y;
          sreg[q * 4 + 2] = v.z; sreg[q * 4 + 3] = v.w;
        }
      } else {
        #pragma unroll
        for (int r = 0; r < 16; ++r) sreg[r] = hb[(cc + 1) * 4096 + r * 256 + tid];
      }
    }

    #pragma unroll 2
    for (int icl = 0; icl < 16; ++icl) {
      float vt[4][3];
      const float* ip = &ins[icl][y2 * 2 * 18 + x];
      #pragma unroll
      for (int r = 0; r < 4; ++r)
        #pragma unroll
        for (int cxx = 0; cxx < 3; ++cxx)
          vt[r][cxx] = ip[r * 18 + cxx];

      int ic = cc * 16 + icl;
      #pragma unroll
      for (int j = 0; j < 4; ++j) {
        const float* wp = &wsh[((ocg * 4 + j) * 64 + ic) * 12];
        float4 wa = *reinterpret_cast<const float4*>(wp);
        float4 wb = *reinterpret_cast<const float4*>(wp + 4);
        float w8 = wp[8];
        float wv[9] = {wa.x, wa.y, wa.z, wa.w, wb.x, wb.y, wb.z, wb.w, w8};
        float a0 = acc[j][0], a1 = acc[j][1];
        #pragma unroll
        for (int dy = 0; dy < 3; ++dy)
          #pragma unroll
          for (int dx = 0; dx < 3; ++dx) {
            float wt = wv[dy * 3 + dx];
            a0 = __builtin_fmaf(vt[dy][dx], wt, a0);
            a1 = __builtin_fmaf(vt[dy + 1][dx], wt, a1);
          }
        acc[j][0] = a0; acc[j][1] = a1;
      }
    }
  }

  #pragma unroll
  for (int j = 0; j < 4; ++j) {
    int oc = ocb * 8 + ocg * 4 + j;
    #pragma unroll
    for (int r = 0; r < 2; ++r) {
      int pix = (y2 * 2 + r) * 16 + x;
      size_t gi = ((size_t)b * 64 + oc) * NPIX + pix;
      float h = use_tok ? emb[(size_t)tok_s[pix] * 64 + oc] : hup[gi];
      float ho = 0.5f * h + 0.5f * acc[j][r];
      out[gi] += ho;
      zr[gi]  -= ho;
    }
  }
}

extern "C" void kernel_launch(void* const* d_in, const int* in_sizes, int n_in,
                              void* d_out, int out_size, void* d_ws, size_t ws_size,
                              hipStream_t stream) {
  const float* f    = (const float*)d_in[0];
  const float* emb  = (const float*)d_in[1];
  const float* phiw = (const float*)d_in[2];
  const float* phib = (const float*)d_in[3];
  float* out = (float*)d_out;

  float* ws  = (float*)d_ws;
  float* zr     = ws;                        // 524288
  float* zd     = ws + 524288;               // 32768 (si0 only)
  float* hup    = ws + 557056;               // 524288
  float* wsq32  = ws + 1081344;              // 8192
  float* pd     = ws + 1089536;              // 8192
  int*   pi     = (int*)(ws + 1097728);      // 8192
  u16*   zhi    = (u16*)(ws + 1105920);      // 524288 u16 = 262144 f
  u16*   ehi    = (u16*)(ws + 1368064);      // 524288 u16 = 262144 f
  float* cand_d = ws + 1630208;              // 1048576 (8192 vec x 128 keys)
  float* zsq32  = ws + 2678784;              // 8192
  float* zt32   = ws + 2686976;              // 524288
  float* nhw    = ws + 3211264;              // 8192
  // end 3219456 floats = 12.88 MB

  // PHI_IDX (numpy linspace argmin in doubles)
  double start = 1.0 / 3.0 / 4.0;
  double stop  = 1.0 - 1.0 / 3.0 / 4.0;
  double step  = (stop - start) / 3.0;
  double ticks[4] = { start, 1.0 * step + start, 2.0 * step + start, stop };
  int phi_idx[5];
  for (int si = 0; si < 5; ++si) {
    double xx = si / 4.0;
    int bj = 0; double bdd = fabs(ticks[0] - xx);
    for (int j = 1; j < 4; ++j) { double dd = fabs(ticks[j] - xx); if (dd < bdd) { bdd = dd; bj = j; } }
    phi_idx[si] = bj;
  }

  static const int MSarr[5] = {1, 2, 4, 8, 16};

  k_prep<<<NELEM / 256, 256, 0, stream>>>(f, zr, out, emb, wsq32, nhw, ehi);

  // si0: exact path; si>=1: MFMA path (part=256, ncand=128)
  const int KS[5] = {128, 32, 32, 32, 32};
  for (int si = 0; si < 5; ++si) {
    int pn = MSarr[si], pnpn = pn * pn, numVec = BB * pnpn;
    int ksplit = KS[si];
    if (si >= 1) {
      int bs = 16 / pn;                       // 8 (si1), 4 (si2), 2 (si3), 1 (si4)
      int part = KK / ksplit;                 // 256
      k_pack<<<numVec / 4, 256, 0, stream>>>(zr, pn, bs, zhi, zt32, zsq32);
      dim3 g((numVec + 127) / 128, ksplit);
      k_argmin_mfma<<<g, 256, 0, stream>>>(zhi, ehi, nhw, cand_d, numVec, part);
      k_rescore<<<numVec / 4, 256, 0, stream>>>(cand_d, zt32, emb,
                                                wsq32, zsq32, pi,
                                                numVec, ksplit * 4);
      if (si < 4)
        k_up<<<NELEM / 256, 256, 0, stream>>>(pd, pi, emb, hup, pn, 1);
    } else {
      int n = BB * CC * pnpn;
      k_down<<<(n + 255) / 256, 256, 0, stream>>>(zr, zd, pn);
      int kchunk = KK / ksplit;
      dim3 g((numVec + 31) / 32, ksplit);
      k_argmin<<<g, 256, 0, stream>>>(zd, emb, wsq32, pd, pi, numVec, pnpn, kchunk);
      k_up<<<NELEM / 256, 256, 0, stream>>>(pd, pi, emb, hup, pn, ksplit);
    }
    int pidx = phi_idx[si];
    k_conv<<<dim3(BB, 8), 256, 0, stream>>>(hup, phiw + pidx * 64 * 64 * 9,
                                            phib + pidx * 64, out, zr,
                                            pi, emb, si == 4 ? 1 : 0);
  }
}

// Round 20
// 272.655 us; speedup vs baseline: 1.0124x; 1.0124x over previous
//
#include <hip/hip_runtime.h>
#include <math.h>
#include <float.h>

#define BB 32
#define CC 64
#define KK 8192
#define NPIX 256
#define NELEM (BB*CC*NPIX)  // 524288

typedef unsigned short u16;
typedef __attribute__((ext_vector_type(8))) short bf16x8;
typedef __attribute__((ext_vector_type(4))) float f32x4;

__device__ __forceinline__ u16 f2bf(float v) {   // RNE f32->bf16
  unsigned u = __float_as_uint(v);
  return (u16)((u + 0x7FFFu + ((u >> 16) & 1u)) >> 16);
}

// init zr/out + wsq (+ -wsq/2) + ehi(bf16 pack of emb) in one launch
__global__ void k_prep(const float* __restrict__ f, float* __restrict__ zr,
                       float* __restrict__ out, const float* __restrict__ emb,
                       float* __restrict__ wsq32, float* __restrict__ nhw,
                       u16* __restrict__ ehi) {
  int i = blockIdx.x * 256 + threadIdx.x;
  if (i < NELEM) { zr[i] = f[i]; out[i] = 0.f; ehi[i] = f2bf(emb[i]); }
  if (i < KK) {
    const float* row = emb + i * 64;
    double s = 0.0;
    #pragma unroll
    for (int c = 0; c < 64; ++c) s += (double)row[c] * (double)row[c];
    float w = (float)s;
    wsq32[i] = w;            // same-binade f32: argmin-safe (scheme-free)
    nhw[i] = -0.5f * w;      // prefilter accumulator init
  }
}

// numpy-exact area mean for si0 (pn=1): feeds exact argmin path
__global__ void k_down(const float* __restrict__ zr, float* __restrict__ zd, int pn) {
#pragma clang fp contract(off)
  int i = blockIdx.x * 256 + threadIdx.x;
  int pnpn = pn * pn;
  int n = BB * CC * pnpn;
  if (i >= n) return;
  int x = i % pn; int y = (i / pn) % pn; int bc = i / pnpn;
  int bs = 16 / pn;
  const float* src = zr + bc * NPIX + (y * bs) * 16 + x * bs;
  float acc = 0.f;
  for (int dy = 0; dy < bs; ++dy) {
    const float* a = src + dy * 16;
    float s;
    if (bs == 16) {
      float r[8];
      #pragma unroll
      for (int j = 0; j < 8; ++j) r[j] = a[j] + a[8 + j];
      s = ((r[0] + r[1]) + (r[2] + r[3])) + ((r[4] + r[5]) + (r[6] + r[7]));
    } else if (bs == 8) {
      s = ((a[0] + a[1]) + (a[2] + a[3])) + ((a[4] + a[5]) + (a[6] + a[7]));
    } else if (bs == 4) {
      s = ((a[0] + a[1]) + a[2]) + a[3];
    } else {
      s = a[0] + a[1];
    }
    acc = acc + s;
  }
  zd[i] = acc * (1.f / (bs * bs));
}

// pack for MFMA path: lane-per-channel. bs=1 (si4), 2 (si3), 4 (si2), 8 (si1):
// fused numpy-exact area mean. Writes zhi(bf16), zt32(f32), zsq32.
__global__ __launch_bounds__(256) void k_pack(
    const float* __restrict__ zr, int pn, int bs,
    u16* __restrict__ zhi, float* __restrict__ zt32, float* __restrict__ zsq32) {
#pragma clang fp contract(off)
  int tid = threadIdx.x;
  int lv = tid >> 6, c = tid & 63;
  int vec = blockIdx.x * 4 + lv;
  int pnpn = pn * pn;
  int b = vec / pnpn, p = vec % pnpn;
  int y = p / pn, x = p % pn;
  const float* src = zr + ((size_t)(b * 64 + c)) * 256 + (y * bs) * 16 + x * bs;
  float v;
  if (bs == 1) {
    v = src[0];
  } else if (bs == 2) {   // rows: a0+a1; sequential rows; * exact 0.25
    v = (src[0] + src[1]) + (src[16] + src[17]);
    v = v * 0.25f;
  } else if (bs == 4) {   // rows ((a0+a1)+a2)+a3; seq rows; * 1/16
    float acc = 0.f;
    #pragma unroll
    for (int dy = 0; dy < 4; ++dy) {
      const float* a = src + dy * 16;
      float s = ((a[0] + a[1]) + a[2]) + a[3];
      acc = acc + s;
    }
    v = acc * 0.0625f;
  } else {                // bs==8: pairwise-tree rows; seq rows; * 1/64
    float acc = 0.f;
    #pragma unroll
    for (int dy = 0; dy < 8; ++dy) {
      const float* a = src + dy * 16;
      float s = ((a[0] + a[1]) + (a[2] + a[3])) + ((a[4] + a[5]) + (a[6] + a[7]));
      acc = acc + s;
    }
    v = acc * 0.015625f;
  }
  zhi[(size_t)vec * 64 + c] = f2bf(v);
  zt32[(size_t)vec * 64 + c] = v;
  double sq = (double)v * (double)v;
  #pragma unroll
  for (int m = 1; m < 64; m <<= 1)
    sq += __shfl_xor(sq, m, 64);        // f64 all-reduce: order-independent to 1e-15
  if (c == 0) zsq32[vec] = (float)sq;
}

// ---- argmin, si0 only (exact path, proven) ----
__global__ __launch_bounds__(256, 4) void k_argmin(
    const float* __restrict__ zd, const float* __restrict__ emb,
    const float* __restrict__ wsq32,
    float* __restrict__ pd, int* __restrict__ pi,
    int numVec, int pnpn, int kchunk) {
#pragma clang fp contract(off)
  __shared__ __align__(16) float zt[32][68];
  __shared__ __align__(16) float et[64 * 64];
  __shared__ float ws_s[64];
  __shared__ float red_d[256];
  __shared__ int   red_i[256];
  int tid = threadIdx.x;
  int v0 = blockIdx.x * 32;
  int kbase = blockIdx.y * kchunk;

  for (int idx = tid; idx < 32 * 64; idx += 256) {
    int v = idx >> 6, c = idx & 63;
    int vi = v0 + v;
    float val = 0.f;
    if (vi < numVec) {
      int b = vi / pnpn, p = vi % pnpn;
      val = zd[(b * 64 + c) * pnpn + p];
    }
    zt[v][c] = val;
  }
  __syncthreads();

  const int v = tid & 31, kg = tid >> 5;
  float4 z4[16];
  #pragma unroll
  for (int i = 0; i < 16; ++i) z4[i] = *reinterpret_cast<float4*>(&zt[v][i * 4]);
  float zsq = 0.f;
  #pragma unroll
  for (int i = 0; i < 16; ++i)
    zsq += z4[i].x * z4[i].x + z4[i].y * z4[i].y + z4[i].z * z4[i].z + z4[i].w * z4[i].w;

  float bd = FLT_MAX; int bi = 0x7fffffff;
  for (int k0 = 0; k0 < kchunk; k0 += 64) {
    __syncthreads();
    {
      const float4* gsrc = reinterpret_cast<const float4*>(emb + (size_t)(kbase + k0) * 64);
      float4* ldst = reinterpret_cast<float4*>(et);
      #pragma unroll
      for (int idx = 0; idx < 4; ++idx)
        ldst[tid + idx * 256] = gsrc[tid + idx * 256];
    }
    if (tid < 64) ws_s[tid] = wsq32[kbase + k0 + tid];
    __syncthreads();
    #pragma unroll
    for (int j = 0; j < 8; ++j) {
      int kl = kg * 8 + j;
      const float4* e4 = reinterpret_cast<const float4*>(&et[kl * 64]);
      float acc = 0.f;
      #pragma unroll
      for (int i = 0; i < 16; ++i) {
        float4 e = e4[i];
        acc = __builtin_fmaf(z4[i].x, e.x, acc);
        acc = __builtin_fmaf(z4[i].y, e.y, acc);
        acc = __builtin_fmaf(z4[i].z, e.z, acc);
        acc = __builtin_fmaf(z4[i].w, e.w, acc);
      }
      float t1 = zsq + ws_s[kl];
      float d  = t1 - 2.0f * acc;
      if (d < bd) { bd = d; bi = kbase + k0 + kl; }
    }
  }
  red_d[tid] = bd; red_i[tid] = bi;
  __syncthreads();
  if (tid < 32) {
    float fb = red_d[tid]; int fi = red_i[tid];
    #pragma unroll
    for (int g = 1; g < 8; ++g) {
      float cd = red_d[g * 32 + tid]; int ci = red_i[g * 32 + tid];
      if (cd < fb || (cd == fb && ci < fi)) { fb = cd; fi = ci; }
    }
    int vi = v0 + tid;
    if (vi < numVec) {
      pd[blockIdx.y * numVec + vi] = fb;
      pi[blockIdx.y * numVec + vi] = fi;
    }
  }
}

// ---- argmin big scales: bf16 MFMA prefilter, MAX-form packed keys,
// ASYNC double-buffer at (256,4): prefetch next tile to registers during
// compute; ds_write after compute (proven r17: no spill, FETCH sane).
__global__ __launch_bounds__(256, 4) void k_argmin_mfma(
    const u16* __restrict__ zhi, const u16* __restrict__ ehi,
    const float* __restrict__ nhw, float* __restrict__ cdp,
    int numVec, int part) {
  __shared__ u16  es[2][64 * 72];
  __shared__ float wss[2][64];
  const int tid = threadIdx.x;
  const int wid = tid >> 6, lane = tid & 63;
  const int l15 = lane & 15, l4 = lane >> 4;
  const int vw = blockIdx.x * 128 + wid * 32;
  const int kbase = blockIdx.y * part;
  const int KSx = gridDim.y;

  bf16x8 za[2][2];
  #pragma unroll
  for (int s = 0; s < 2; ++s) {
    const u16* zp = zhi + (size_t)(vw + s * 16 + l15) * 64 + l4 * 8;
    za[s][0] = *reinterpret_cast<const bf16x8*>(zp);
    za[s][1] = *reinterpret_cast<const bf16x8*>(zp + 32);
  }

  float d1[2][4], d2[2][4];
  #pragma unroll
  for (int s = 0; s < 2; ++s)
    #pragma unroll
    for (int r = 0; r < 4; ++r) { d1[s][r] = -FLT_MAX; d2[s][r] = -FLT_MAX; }

  const int NT = part >> 6;
  bf16x8 r0, r1; float wreg = 0.f;
  const int scode = tid >> 2, sseg = tid & 3;

  #define LOADT(t)                                                           \
    { const bf16x8* s8 = reinterpret_cast<const bf16x8*>(                    \
          ehi + (size_t)(kbase + (t) * 64) * 64 + scode * 64 + sseg * 16);   \
      r0 = s8[0]; r1 = s8[1];                                                \
      if (tid < 64) wreg = nhw[kbase + (t) * 64 + tid]; }
  #define WRITET(buf)                                                        \
    { bf16x8* d8 = reinterpret_cast<bf16x8*>(&es[buf][scode * 72 + sseg * 16]); \
      d8[0] = r0; d8[1] = r1;                                                \
      if (tid < 64) wss[buf][tid] = wreg; }

  LOADT(0); WRITET(0);
  __syncthreads();
  for (int t = 0; t < NT; ++t) {
    int cur = t & 1;
    if (t + 1 < NT) LOADT(t + 1);        // in-flight during compute
    #pragma unroll
    for (int ct = 0; ct < 4; ++ct) {
      const u16* eb = &es[cur][(ct * 16 + l15) * 72 + l4 * 8];
      bf16x8 b0 = *reinterpret_cast<const bf16x8*>(eb);
      bf16x8 b1 = *reinterpret_cast<const bf16x8*>(eb + 32);
      float hwl = wss[cur][ct * 16 + l15];           // = -wsq/2
      unsigned idu = (unsigned)(t * 64 + ct * 16 + l15);   // < 256
      #pragma unroll
      for (int s = 0; s < 2; ++s) {
        f32x4 acc = {hwl, hwl, hwl, hwl};
        acc = __builtin_amdgcn_mfma_f32_16x16x32_bf16(za[s][0], b0, acc, 0, 0, 0);
        acc = __builtin_amdgcn_mfma_f32_16x16x32_bf16(za[s][1], b1, acc, 0, 0, 0);
        #pragma unroll
        for (int r = 0; r < 4; ++r) {
          // v_bfi_b32 pattern: (x & M) | (id & ~M)
          unsigned ku = (__float_as_uint(acc[r]) & 0xFFFFFF00u) | (idu & 0x000000FFu);
          float key = __uint_as_float(ku);
          float o1 = d1[s][r];
          d1[s][r] = fmaxf(o1, key);
          d2[s][r] = __builtin_amdgcn_fmed3f(o1, key, d2[s][r]);
        }
      }
    }
    if (t + 1 < NT) WRITET(cur ^ 1);     // vmcnt wait lands after compute
    __syncthreads();
  }

  // merge: top-2 per 8-lane half (masks 1,2,4), write 4 keys/part
  #pragma unroll
  for (int s = 0; s < 2; ++s)
    #pragma unroll
    for (int r = 0; r < 4; ++r) {
      float q0 = d1[s][r], q1 = d2[s][r];
      #pragma unroll
      for (int m = 1; m < 8; m <<= 1) {
        float p0 = __shfl_xor(q0, m), p1 = __shfl_xor(q1, m);
        { bool c0 = p0 > q0, c1 = p0 > q1;
          q1 = c0 ? q0 : (c1 ? p0 : q1);
          q0 = c0 ? p0 : q0; }
        { bool c0 = p1 > q0, c1 = p1 > q1;
          q1 = c0 ? q0 : (c1 ? p1 : q1);
          q0 = c0 ? p1 : q0; }
      }
      if ((l15 & 7) == 0) {
        int vec = vw + s * 16 + l4 * 4 + r;
        int half = l15 >> 3;
        size_t base = ((size_t)vec * KSx + blockIdx.y) * 4 + half * 2;
        cdp[base + 0] = q0; cdp[base + 1] = q1;
      }
    }
}

// exact rescore: wave-per-vector, lane-per-candidate (2 slots, ncand=128).
// keys are MAX-form (acc = dot - wl/2); band: key >= amax - band/2.
// Writes tok (pi) only — downstream k_up uses the ksplit==1 fast path.
__global__ __launch_bounds__(256) void k_rescore(
    const float* __restrict__ cdp, const float* __restrict__ zt32,
    const float* __restrict__ emb, const float* __restrict__ wsq32,
    const float* __restrict__ zsq32,
    int* __restrict__ pi, int numVec, int ncand) {
#pragma clang fp contract(off)
  __shared__ float zsh[4][64];
  int tid = threadIdx.x;
  int wid = tid >> 6, lane = tid & 63;
  int v0 = blockIdx.x * 4;
  zsh[wid][lane] = zt32[(size_t)v0 * 64 + tid];
  __syncthreads();

  int vec = v0 + wid;
  float zsq = zsq32[vec];
  const float* cdb = cdp + (size_t)vec * ncand;
  float dv0 = cdb[lane];
  float dv1 = (ncand > 64) ? cdb[lane + 64] : -FLT_MAX;
  int j0 = lane, j1 = lane + 64;
  int ki0 = ((j0 >> 2) << 8) | (int)(__float_as_uint(dv0) & 0xFFu);
  int ki1 = ((j1 >> 2) << 8) | (int)(__float_as_uint(dv1) & 0xFFu);

  float amax = fmaxf(dv0, dv1);
  #pragma unroll
  for (int m = 1; m < 64; m <<= 1) amax = fmaxf(amax, __shfl_xor(amax, m, 64));
  float thr = amax - 0.5f * fmaf(sqrtf(zsq), 1.25e-5f, 1e-4f);

  const float* zw = zsh[wid];
  float d = FLT_MAX; int bi = 0x7fffffff;
  #pragma unroll
  for (int slot = 0; slot < 2; ++slot) {
    float dv = slot ? dv1 : dv0;
    int   kk = slot ? ki1 : ki0;
    if (dv >= thr) {
      const float4* er = reinterpret_cast<const float4*>(emb + (size_t)kk * 64);
      float4 e4[16];
      #pragma unroll
      for (int i = 0; i < 16; ++i) e4[i] = er[i];
      float acc = 0.f;
      #pragma unroll
      for (int i = 0; i < 16; ++i) {               // exact ascending-c chain
        acc = __builtin_fmaf(zw[4 * i + 0], e4[i].x, acc);
        acc = __builtin_fmaf(zw[4 * i + 1], e4[i].y, acc);
        acc = __builtin_fmaf(zw[4 * i + 2], e4[i].z, acc);
        acc = __builtin_fmaf(zw[4 * i + 3], e4[i].w, acc);
      }
      float t1 = zsq + wsq32[kk];
      float dd = t1 - 2.0f * acc;
      if (dd < d || (dd == d && kk < bi)) { d = dd; bi = kk; }
    }
  }
  #pragma unroll
  for (int m = 1; m < 64; m <<= 1) {
    float od = __shfl_xor(d, m, 64);
    int   oi = __shfl_xor(bi, m, 64);
    if (od < d || (od == d && oi < bi)) { d = od; bi = oi; }
  }
  if (lane == 0) pi[vec] = bi;
}

// ---- fused ksplit-reduce + cubic upsample ----
// ksplit==1 (MFMA path): fast path, tok loaded directly from pi.
__global__ __launch_bounds__(256) void k_up(
    const float* __restrict__ pd, const int* __restrict__ pi,
    const float* __restrict__ emb, float* __restrict__ hup,
    int pn, int ksplit) {
  __shared__ float td[256];
  __shared__ int   ti[256];
  __shared__ int   tok_s[256];
  __shared__ float wsh[16][4];
  __shared__ int   i0sh[16];

  int t = threadIdx.x;
  int i = blockIdx.x * 256 + t;
  int p = i & 255; int c = (i >> 8) & 63; int b = i >> 14;
  int P = pn * pn;
  int numVec = BB * P;

  if (ksplit > 1) {
    int R = 256 / P;
    int v = t % P, sg = t / P;
    float bd = FLT_MAX; int bi = 0x7fffffff;
    for (int s = sg; s < ksplit; s += R) {
      float cd = pd[s * numVec + b * P + v]; int ci = pi[s * numVec + b * P + v];
      if (cd < bd || (cd == bd && ci < bi)) { bd = cd; bi = ci; }
    }
    td[t] = bd; ti[t] = bi;
    __syncthreads();
    for (int r = R >> 1; r >= 1; r >>= 1) {
      if (sg < r) {
        float cd = td[t + r * P]; int ci = ti[t + r * P];
        if (cd < td[t] || (cd == td[t] && ci < ti[t])) { td[t] = cd; ti[t] = ci; }
      }
      __syncthreads();
    }
    if (t < P) tok_s[t] = ti[t];
  } else {
    if (t < P) tok_s[t] = pi[b * P + t];   // rescore already reduced
  }
  if (pn < 16 && t < 16) {
    double s = (t + 0.5) * ((double)pn / 16.0) - 0.5;
    int i0 = (int)floor(s) - 1;
    int hi = pn - 4; if (hi < 0) hi = 0;
    if (i0 < 0) i0 = 0; if (i0 > hi) i0 = hi;
    double wv[4]; double sum = 0.0;
    #pragma unroll
    for (int qq = 0; qq < 4; ++qq) {
      int ii = i0 + qq;
      double w = 0.0;
      if (ii < pn) {
        double xx = fabs(s - (double)ii);
        if (xx < 1.0)       w = ((1.5 * xx - 2.5) * xx) * xx + 1.0;
        else if (xx < 2.0)  w = ((-0.5 * xx + 2.5) * xx - 4.0) * xx + 2.0;
      }
      wv[qq] = w; sum += w;
    }
    i0sh[t] = i0;
    #pragma unroll
    for (int qq = 0; qq < 4; ++qq) wsh[t][qq] = (float)(wv[qq] / sum);
  }
  __syncthreads();

  if (pn == 16) { hup[i] = emb[(size_t)tok_s[p] * 64 + c]; return; }

  int y = p >> 4, x = p & 15;
  int iy0 = i0sh[y], ix0 = i0sh[x];
  float acc = 0.f;
  #pragma unroll
  for (int ty = 0; ty < 4; ++ty) {
    float wy = wsh[y][ty];
    int iy = iy0 + ty; if (iy > pn - 1) iy = pn - 1;
    float tmp = 0.f;
    #pragma unroll
    for (int tx = 0; tx < 4; ++tx) {
      float wx = wsh[x][tx];
      int ix = ix0 + tx; if (ix > pn - 1) ix = pn - 1;
      tmp += wx * emb[(size_t)tok_s[iy * pn + ix] * 64 + c];
    }
    acc += wy * tmp;
  }
  hup[i] = acc;
}

// ---- conv (round-8 proven version) ----
__global__ __launch_bounds__(256) void k_conv(
    const float* __restrict__ hup, const float* __restrict__ w,
    const float* __restrict__ bias, float* __restrict__ out, float* __restrict__ zr) {
  __shared__ __align__(16) float ins[16][18 * 18];
  __shared__ __align__(16) float wsh[8 * 64 * 12];
  int tid = threadIdx.x;
  int b = blockIdx.x;
  int ocb = blockIdx.y;

  for (int idx = tid; idx < 16 * 324; idx += 256)
    (&ins[0][0])[idx] = 0.f;
  for (int idx = tid; idx < 8 * 64 * 9; idx += 256) {
    int ocic = idx / 9, t = idx - ocic * 9;
    wsh[ocic * 12 + t] = w[(size_t)ocb * 8 * 64 * 9 + idx];
  }

  const int wid = tid >> 6, lane = tid & 63;
  const int ocg = wid >> 1;
  const int ph = (wid & 1) * 64 + lane;
  const int x = ph & 15, y2 = ph >> 4;

  float acc[4][2];
  #pragma unroll
  for (int j = 0; j < 4; ++j) {
    float bv = bias[ocb * 8 + ocg * 4 + j];
    acc[j][0] = bv; acc[j][1] = bv;
  }

  const float* hb = hup + (size_t)b * 64 * NPIX;
  float sreg[16];
  #pragma unroll
  for (int r = 0; r < 16; ++r) sreg[r] = hb[r * 256 + tid];

  for (int cc = 0; cc < 4; ++cc) {
    __syncthreads();
    #pragma unroll
    for (int r = 0; r < 16; ++r) {
      int idx = r * 256 + tid;
      int icl = idx >> 8, p = idx & 255;
      ins[icl][((p >> 4) + 1) * 18 + (p & 15) + 1] = sreg[r];
    }
    __syncthreads();
    if (cc < 3) {
      #pragma unroll
      for (int r = 0; r < 16; ++r) sreg[r] = hb[(cc + 1) * 4096 + r * 256 + tid];
    }

    #pragma unroll 2
    for (int icl = 0; icl < 16; ++icl) {
      float vt[4][3];
      const float* ip = &ins[icl][y2 * 2 * 18 + x];
      #pragma unroll
      for (int r = 0; r < 4; ++r)
        #pragma unroll
        for (int cxx = 0; cxx < 3; ++cxx)
          vt[r][cxx] = ip[r * 18 + cxx];

      int ic = cc * 16 + icl;
      #pragma unroll
      for (int j = 0; j < 4; ++j) {
        const float* wp = &wsh[((ocg * 4 + j) * 64 + ic) * 12];
        float4 wa = *reinterpret_cast<const float4*>(wp);
        float4 wb = *reinterpret_cast<const float4*>(wp + 4);
        float w8 = wp[8];
        float wv[9] = {wa.x, wa.y, wa.z, wa.w, wb.x, wb.y, wb.z, wb.w, w8};
        float a0 = acc[j][0], a1 = acc[j][1];
        #pragma unroll
        for (int dy = 0; dy < 3; ++dy)
          #pragma unroll
          for (int dx = 0; dx < 3; ++dx) {
            float wt = wv[dy * 3 + dx];
            a0 = __builtin_fmaf(vt[dy][dx], wt, a0);
            a1 = __builtin_fmaf(vt[dy + 1][dx], wt, a1);
          }
        acc[j][0] = a0; acc[j][1] = a1;
      }
    }
  }

  #pragma unroll
  for (int j = 0; j < 4; ++j) {
    int oc = ocb * 8 + ocg * 4 + j;
    #pragma unroll
    for (int r = 0; r < 2; ++r) {
      size_t gi = ((size_t)b * 64 + oc) * NPIX + (y2 * 2 + r) * 16 + x;
      float h = hup[gi];
      float ho = 0.5f * h + 0.5f * acc[j][r];
      out[gi] += ho;
      zr[gi]  -= ho;
    }
  }
}

extern "C" void kernel_launch(void* const* d_in, const int* in_sizes, int n_in,
                              void* d_out, int out_size, void* d_ws, size_t ws_size,
                              hipStream_t stream) {
  const float* f    = (const float*)d_in[0];
  const float* emb  = (const float*)d_in[1];
  const float* phiw = (const float*)d_in[2];
  const float* phib = (const float*)d_in[3];
  float* out = (float*)d_out;

  float* ws  = (float*)d_ws;
  float* zr     = ws;                        // 524288
  float* zd     = ws + 524288;               // 32768 (si0 only)
  float* hup    = ws + 557056;               // 524288
  float* wsq32  = ws + 1081344;              // 8192
  float* pd     = ws + 1089536;              // 8192
  int*   pi     = (int*)(ws + 1097728);      // 8192
  u16*   zhi    = (u16*)(ws + 1105920);      // 524288 u16 = 262144 f
  u16*   ehi    = (u16*)(ws + 1368064);      // 524288 u16 = 262144 f
  float* cand_d = ws + 1630208;              // 1048576 (8192 vec x 128 keys)
  float* zsq32  = ws + 2678784;              // 8192
  float* zt32   = ws + 2686976;              // 524288
  float* nhw    = ws + 3211264;              // 8192
  // end 3219456 floats = 12.88 MB

  // PHI_IDX (numpy linspace argmin in doubles)
  double start = 1.0 / 3.0 / 4.0;
  double stop  = 1.0 - 1.0 / 3.0 / 4.0;
  double step  = (stop - start) / 3.0;
  double ticks[4] = { start, 1.0 * step + start, 2.0 * step + start, stop };
  int phi_idx[5];
  for (int si = 0; si < 5; ++si) {
    double xx = si / 4.0;
    int bj = 0; double bdd = fabs(ticks[0] - xx);
    for (int j = 1; j < 4; ++j) { double dd = fabs(ticks[j] - xx); if (dd < bdd) { bdd = dd; bj = j; } }
    phi_idx[si] = bj;
  }

  static const int MSarr[5] = {1, 2, 4, 8, 16};

  k_prep<<<NELEM / 256, 256, 0, stream>>>(f, zr, out, emb, wsq32, nhw, ehi);

  // si0: exact path; si>=1: MFMA path (part=256, ncand=128)
  const int KS[5] = {128, 32, 32, 32, 32};
  for (int si = 0; si < 5; ++si) {
    int pn = MSarr[si], pnpn = pn * pn, numVec = BB * pnpn;
    int ksplit = KS[si];
    if (si >= 1) {
      int bs = 16 / pn;                       // 8 (si1), 4 (si2), 2 (si3), 1 (si4)
      int part = KK / ksplit;                 // 256
      k_pack<<<numVec / 4, 256, 0, stream>>>(zr, pn, bs, zhi, zt32, zsq32);
      dim3 g((numVec + 127) / 128, ksplit);
      k_argmin_mfma<<<g, 256, 0, stream>>>(zhi, ehi, nhw, cand_d, numVec, part);
      k_rescore<<<numVec / 4, 256, 0, stream>>>(cand_d, zt32, emb,
                                                wsq32, zsq32, pi,
                                                numVec, ksplit * 4);
      k_up<<<NELEM / 256, 256, 0, stream>>>(pd, pi, emb, hup, pn, 1);
    } else {
      int n = BB * CC * pnpn;
      k_down<<<(n + 255) / 256, 256, 0, stream>>>(zr, zd, pn);
      int kchunk = KK / ksplit;
      dim3 g((numVec + 31) / 32, ksplit);
      k_argmin<<<g, 256, 0, stream>>>(zd, emb, wsq32, pd, pi, numVec, pnpn, kchunk);
      k_up<<<NELEM / 256, 256, 0, stream>>>(pd, pi, emb, hup, pn, ksplit);
    }
    int pidx = phi_idx[si];
    k_conv<<<dim3(BB, 8), 256, 0, stream>>>(hup, phiw + pidx * 64 * 64 * 9,
                                            phib + pidx * 64, out, zr);
  }
}